// Round 16
// baseline (114.948 us; speedup 1.0000x reference)
//
#include <hip/hip_runtime.h>
#include <hip/hip_bf16.h>
#include <stdint.h>

#define B_ 8
#define T_ 2304
#define DIN 1024
#define LAMBDA_INIT_F 0.6192834728526788f
#define QSCALE 0.1803368801111137f   // 0.125 * log2(e); softmax runs in base-2

typedef __bf16 bf16x8 __attribute__((ext_vector_type(8)));
typedef float f32x4 __attribute__((ext_vector_type(4)));

__device__ __forceinline__ unsigned short f2bf(float f) {
    union { float f; unsigned int u; } v; v.f = f;
    unsigned int u = v.u;
    unsigned int r = (u + 0x7FFFu + ((u >> 16) & 1u)) >> 16;
    return (unsigned short)r;
}

__device__ __forceinline__ unsigned int pack2bf(float lo, float hi) {
    return ((unsigned int)f2bf(hi) << 16) | (unsigned int)f2bf(lo);
}

// native bf16 pair conversion (compiler emits v_cvt, fuses pairs)
__device__ __forceinline__ unsigned int cvt2bf(float lo, float hi) {
    union { __bf16 h[2]; unsigned int u; } v;
    v.h[0] = (__bf16)lo; v.h[1] = (__bf16)hi;
    return v.u;
}

__device__ __forceinline__ float bf2f(unsigned short u) {
    union { unsigned int u; float f; } v; v.u = ((unsigned int)u) << 16;
    return v.f;
}

// async 16B global->LDS (lane i writes lds_base + i*16; lds base wave-uniform)
__device__ __forceinline__ void gload16(const void* g, void* l) {
    __builtin_amdgcn_global_load_lds(
        (const __attribute__((address_space(1))) unsigned int*)g,
        (__attribute__((address_space(3))) unsigned int*)l,
        16, 0, 0);
}

// ---------------------------------------------------------------------------
// Kernel 1: transpose 9 weight mats (1024x128 f32) -> WT[seg][384][1024] bf16
// ---------------------------------------------------------------------------
__global__ __launch_bounds__(256) void k_wtrans(
    const float* w0, const float* w1, const float* w2,
    const float* w3, const float* w4, const float* w5,
    const float* w6, const float* w7, const float* w8,
    unsigned short* __restrict__ wt)
{
    __shared__ float tile[64][65];
    int bx = blockIdx.x;
    int mat = bx >> 5;
    int tl = bx & 31;
    int tx = tl & 15;
    int ty = tl >> 4;
    const float* srcs[9] = {w0, w1, w2, w3, w4, w5, w6, w7, w8};
    const float* src = srcs[mat];
    int k0 = tx * 64, c0 = ty * 64;
    int t = threadIdx.x;
    int r = t >> 2, cg = (t & 3) << 4;
    const float* p = src + (size_t)(k0 + r) * 128 + c0 + cg;
#pragma unroll
    for (int i = 0; i < 4; ++i) {
        float4 v = *(const float4*)(p + i * 4);
        tile[r][cg + i * 4 + 0] = v.x;
        tile[r][cg + i * 4 + 1] = v.y;
        tile[r][cg + i * 4 + 2] = v.z;
        tile[r][cg + i * 4 + 3] = v.w;
    }
    __syncthreads();
    int seg = mat / 3, m = mat % 3;
    int crow = seg * 384 + m * 128 + c0 + r;
    unsigned short* dst = wt + (size_t)crow * 1024 + k0 + cg;
    __align__(16) unsigned short ob[16];
#pragma unroll
    for (int i = 0; i < 16; ++i) ob[i] = f2bf(tile[cg + i][r]);
    *(uint4*)(dst) = *(const uint4*)(ob);
    *(uint4*)(dst + 8) = *(const uint4*)(ob + 8);
}

// ---------------------------------------------------------------------------
// Kernel 2: streaming LayerNorm: x f32 -> xbf bf16 [18432][1024].
// ---------------------------------------------------------------------------
__global__ __launch_bounds__(256) void k_ln(
    const float* __restrict__ x,
    const float* __restrict__ g_in, const float* __restrict__ b_in,
    const float* __restrict__ g_ss, const float* __restrict__ b_ss,
    const float* __restrict__ g_se, const float* __restrict__ b_se,
    unsigned short* __restrict__ xbf)
{
    int row = (blockIdx.x << 2) + (threadIdx.x >> 6);
    int l = threadIdx.x & 63;
    int t = row % T_;
    const float* gv; const float* bv;
    if (t < 128)       { gv = g_ss; bv = b_ss; }
    else if (t < 2176) { gv = g_in; bv = b_in; }
    else               { gv = g_se; bv = b_se; }
    const float* xp = x + (size_t)row * DIN + l * 4;
    float4 v0 = *(const float4*)(xp);
    float4 v1 = *(const float4*)(xp + 256);
    float4 v2 = *(const float4*)(xp + 512);
    float4 v3 = *(const float4*)(xp + 768);
    float s  = v0.x + v0.y + v0.z + v0.w + v1.x + v1.y + v1.z + v1.w
             + v2.x + v2.y + v2.z + v2.w + v3.x + v3.y + v3.z + v3.w;
    float s2 = v0.x*v0.x + v0.y*v0.y + v0.z*v0.z + v0.w*v0.w
             + v1.x*v1.x + v1.y*v1.y + v1.z*v1.z + v1.w*v1.w
             + v2.x*v2.x + v2.y*v2.y + v2.z*v2.z + v2.w*v2.w
             + v3.x*v3.x + v3.y*v3.y + v3.z*v3.z + v3.w*v3.w;
#pragma unroll
    for (int off = 1; off <= 32; off <<= 1) {
        s  += __shfl_xor(s,  off);
        s2 += __shfl_xor(s2, off);
    }
    float mean = s * (1.f / 1024.f);
    float rstd = rsqrtf(s2 * (1.f / 1024.f) - mean * mean + 1e-5f);
    unsigned short* op = xbf + (size_t)row * DIN + l * 4;
    const float* gp = gv + l * 4;
    const float* bp = bv + l * 4;
#pragma unroll
    for (int k = 0; k < 4; ++k) {
        float4 vv = (k == 0) ? v0 : (k == 1) ? v1 : (k == 2) ? v2 : v3;
        float4 gk = *(const float4*)(gp + k * 256);
        float4 bk = *(const float4*)(bp + k * 256);
        uint2 o;
        o.x = pack2bf((vv.x - mean) * rstd * gk.x + bk.x,
                      (vv.y - mean) * rstd * gk.y + bk.y);
        o.y = pack2bf((vv.z - mean) * rstd * gk.z + bk.z,
                      (vv.w - mean) * rstd * gk.w + bk.w);
        *(uint2*)(op + k * 256) = o;
    }
}

// ---------------------------------------------------------------------------
// Kernel 3: pure bf16 GEMM: C[18432][384] = xbf @ wt[seg]^T.
// q outputs pre-scaled by 0.125*log2e (softmax in base-2 downstream).
// ---------------------------------------------------------------------------
__global__ __launch_bounds__(512, 4) void k_proj2(
    const unsigned short* __restrict__ xbf,
    const unsigned short* __restrict__ wt,
    unsigned short* __restrict__ qo,
    unsigned short* __restrict__ ko,
    unsigned short* __restrict__ vto)
{
    __shared__ __align__(16) char smem[81920];

    int bid = blockIdx.x;
    int mt = bid >> 1, ch = bid & 1;
    int bb = mt / 18, tt = mt % 18;
    int seg = (tt == 0) ? 0 : ((tt < 17) ? 1 : 2);
    size_t arow0 = (size_t)mt * 128;
    int ncol0 = ch * 192;
    int wrow0 = seg * 384 + ncol0;

    int tid = threadIdx.x;
    int w = tid >> 6, l = tid & 63;
    int wr = w >> 2, wc = w & 3;
    int g4 = l >> 4, cr = l & 15;

    int rA0 = tid >> 3, cS = (tid & 7) << 4;
    const char* srcA0 = (const char*)xbf + (arow0 + rA0) * 2048 + cS;
    const char* srcA1 = srcA0 + (size_t)64 * 2048;
    int dA0 = rA0 * 128 + (cS ^ ((rA0 & 7) << 4));
    int dA1 = dA0 + 64 * 128;
    const char* srcW0 = (const char*)wt + (size_t)(wrow0 + rA0) * 2048 + cS;
    const char* srcW1 = srcW0 + (size_t)64 * 2048;
    const char* srcW2 = srcW0 + (size_t)128 * 2048;
    int dW0 = dA0, dW1 = dA0 + 64 * 128, dW2 = dA0 + 128 * 128;

    {
        uint4 a0 = *(const uint4*)srcA0;
        uint4 a1 = *(const uint4*)srcA1;
        uint4 w0 = *(const uint4*)srcW0;
        uint4 w1 = *(const uint4*)srcW1;
        uint4 w2 = *(const uint4*)srcW2;
        *(uint4*)(smem + dA0) = a0;
        *(uint4*)(smem + dA1) = a1;
        *(uint4*)(smem + 32768 + dW0) = w0;
        *(uint4*)(smem + 32768 + dW1) = w1;
        *(uint4*)(smem + 32768 + dW2) = w2;
    }
    __syncthreads();

    f32x4 acc[4][3] = {};
    for (int ks = 0; ks < 16; ++ks) {
        bool pf = (ks < 15);
        uint4 pa0, pa1, pw0, pw1, pw2;
        if (pf) {
            size_t o = (size_t)(ks + 1) * 128;
            pa0 = *(const uint4*)(srcA0 + o);
            pa1 = *(const uint4*)(srcA1 + o);
            pw0 = *(const uint4*)(srcW0 + o);
            pw1 = *(const uint4*)(srcW1 + o);
            pw2 = *(const uint4*)(srcW2 + o);
        }
        const char* Ab = smem + (ks & 1) * 16384;
        const char* Wb = smem + 32768 + (ks & 1) * 24576;
        __builtin_amdgcn_s_setprio(1);
#pragma unroll
        for (int kk = 0; kk < 2; ++kk) {
            int kb = kk * 64 + g4 * 16;
            bf16x8 af[4];
#pragma unroll
            for (int r4 = 0; r4 < 4; ++r4) {
                int rr = wr * 64 + r4 * 16 + cr;
                af[r4] = *(const bf16x8*)(Ab + rr * 128 + (kb ^ ((rr & 7) << 4)));
            }
            bf16x8 bfr[3];
#pragma unroll
            for (int nt = 0; nt < 3; ++nt) {
                int c = wc * 48 + nt * 16 + cr;
                bfr[nt] = *(const bf16x8*)(Wb + c * 128 + (kb ^ ((c & 7) << 4)));
            }
#pragma unroll
            for (int r4 = 0; r4 < 4; ++r4)
#pragma unroll
                for (int nt = 0; nt < 3; ++nt)
                    acc[r4][nt] = __builtin_amdgcn_mfma_f32_16x16x32_bf16(af[r4], bfr[nt], acc[r4][nt], 0, 0, 0);
        }
        __builtin_amdgcn_s_setprio(0);
        __syncthreads();
        if (pf) {
            char* An = smem + ((ks + 1) & 1) * 16384;
            char* Wn = smem + 32768 + ((ks + 1) & 1) * 24576;
            *(uint4*)(An + dA0) = pa0;
            *(uint4*)(An + dA1) = pa1;
            *(uint4*)(Wn + dW0) = pw0;
            *(uint4*)(Wn + dW1) = pw1;
            *(uint4*)(Wn + dW2) = pw2;
        }
        __syncthreads();
    }

#pragma unroll
    for (int r4 = 0; r4 < 4; ++r4) {
        size_t grow = arow0 + wr * 64 + r4 * 16 + g4 * 4;
#pragma unroll
        for (int nt = 0; nt < 3; ++nt) {
            int c = ncol0 + wc * 48 + nt * 16 + cr;
            f32x4 a = acc[r4][nt];
            if (c < 128) {
#pragma unroll
                for (int g = 0; g < 4; ++g)
                    qo[(grow + g) * 128 + c] = f2bf(a[g] * QSCALE);
            } else if (c < 256) {
#pragma unroll
                for (int g = 0; g < 4; ++g)
                    ko[(grow + g) * 128 + (c - 128)] = f2bf(a[g]);
            } else {
                int cv = c - 256;
                int trow = tt * 128 + wr * 64 + r4 * 16 + g4 * 4;
                uint2 o;
                o.x = pack2bf(a[0], a[1]);
                o.y = pack2bf(a[2], a[3]);
                *(uint2*)(vto + ((size_t)bb * 128 + cv) * T_ + trow) = o;
            }
        }
    }
}

// ---------------------------------------------------------------------------
// Kernel 4: causal diff flash-attention, BRANCH-SPLIT waves.
// 512 threads / 8 waves: wave (qg, br) owns 16 q-rows x ONE branch.
// Per-wave regs ~halve (oacc 32, qf 8, pk 8) -> fits (512,4) cap 128 ->
// 2 blocks/CU = 16 waves/CU. br=0 waves stage K, br=1 waves stage V
// (each role = the proven 256-thread staging map). Math per branch identical.
// ---------------------------------------------------------------------------
__global__ __launch_bounds__(512, 4) void k_attn(
    const unsigned short* __restrict__ qp_,
    const unsigned short* __restrict__ kp_,
    const unsigned short* __restrict__ vp_,
    const float* __restrict__ lq1, const float* __restrict__ lq2,
    const float* __restrict__ lk1, const float* __restrict__ lk2,
    const float* __restrict__ g_out, const float* __restrict__ b_out,
    unsigned short* __restrict__ opart,
    float* __restrict__ mlpart,
    float* __restrict__ out)
{
    __shared__ __align__(16) char smem[32768];   // K 16KB | V 16KB ; epilogue O2 exchange

    int bid = blockIdx.x;
    int b = bid & 7;
    int u = 125 - (bid >> 3);    // big chunks launch first
    int j, ci;
    if (u < 6) { j = u; ci = 0; }
    else {
        int v = u - 6;
        int g, base;
        if (v < 12)      { g = 0; base = 0;  }
        else if (v < 30) { g = 1; base = 12; }
        else if (v < 54) { g = 2; base = 30; }
        else if (v < 84) { g = 3; base = 54; }
        else             { g = 4; base = 84; }
        int w2 = v - base;
        int per = g + 2;
        int qd = w2 / per;
        j = 6 * (g + 1) + qd;
        ci = w2 - qd * per;
    }
    int nch = (j + 6) / 6;
    int c0 = ci * 6;
    int ntile = min(6, j + 1 - c0);
    int t0 = j * 64;

    int tid = threadIdx.x;
    int w8 = tid >> 6;
    int qg = w8 >> 1;            // q sub-tile 0..3
    int br = w8 & 1;             // branch handled by this wave
    int l = tid & 63;
    int g4 = l >> 4, q = l & 15;
    int q_g = t0 + qg * 16 + q;

    // ---- role-based staging maps (K rows permuted for shuffle-free PV) ----
    int ldsRowK = qg * 4 + (l >> 4);
    const char* kSrc0 = (const char*)kp_
                      + ((size_t)b * T_ + qg * 8 + (l >> 4)) * 256
                      + (((l & 15) << 4) ^ ((ldsRowK & 7) << 4));
    int rbV = qg * 8 + (l >> 3);
    const char* vSrc0 = (const char*)vp_ + ((size_t)b * 128 + rbV) * (T_ * 2)
                      + (((l & 7) << 4) ^ ((rbV & 7) << 4));
    char* ldsK = smem + qg * 1024;
    char* ldsV = smem + 16384 + qg * 1024;

    // Q B-fragments (one branch)
    bf16x8 qf[2];
#pragma unroll
    for (int h = 0; h < 2; ++h)
        qf[h] = *(const bf16x8*)(qp_ + ((size_t)b * T_ + q_g) * 128 + br * 64 + h * 32 + g4 * 8);

    // prologue: br0 waves stage K(c0), br1 waves stage V(c0)
    if (br == 0) {
        const char* kS = kSrc0 + (size_t)c0 * 16384;
        gload16(kS,        ldsK);
        gload16(kS + 8192, ldsK + 4096);
        gload16(kS + 1024, ldsK + 8192);
        gload16(kS + 9216, ldsK + 12288);
    } else {
        const char* vS = vSrc0 + (size_t)c0 * 128;
#pragma unroll
        for (int c = 0; c < 4; ++c)
            gload16(vS + (size_t)c * 147456, ldsV + c * 4096);
    }
    __syncthreads();

    float mrun = -1e30f;
    float lrun = 0.f;            // per-lane PARTIAL sum (reduced at end)
    f32x4 oacc[8] = {};
    const char* Kb = smem;
    const char* Vb = smem + 16384;

    for (int t = 0; t < ntile; ++t) {
        int kt = c0 + t;
        bool diag = (kt == j);
        bool pfv = (t + 1 < ntile);
        unsigned int pk[4][2];
        // ---- QK + softmax (one branch; reads K buffer only) ----
        {
            f32x4 s[4] = {};
            __builtin_amdgcn_s_setprio(1);
#pragma unroll
            for (int h = 0; h < 2; ++h) {
#pragma unroll
                for (int t4 = 0; t4 < 4; ++t4) {
                    int rk = t4 * 16 + q;
                    bf16x8 kf = *(const bf16x8*)(Kb + rk * 256 + ((br * 128 + h * 64 + g4 * 16) ^ ((rk & 7) << 4)));
                    s[t4] = __builtin_amdgcn_mfma_f32_16x16x32_bf16(kf, qf[h], s[t4], 0, 0, 0);
                }
            }
            __builtin_amdgcn_s_setprio(0);
            float sv[16];
#pragma unroll
            for (int t4 = 0; t4 < 4; ++t4)
#pragma unroll
                for (int r = 0; r < 4; ++r) {
                    float v = s[t4][r];
                    if (diag) {
                        int kv_g = kt * 64 + (t4 & 1) * 32 + g4 * 8 + (t4 >> 1) * 4 + r;
                        if (kv_g > q_g) v = -1e30f;
                    }
                    sv[t4 * 4 + r] = v;
                }
            // tree max over this lane's 16 values (partial row max)
            float m8[8];
#pragma unroll
            for (int i = 0; i < 8; ++i) m8[i] = fmaxf(sv[i], sv[i + 8]);
            float m4a = fmaxf(m8[0], m8[4]), m4b = fmaxf(m8[1], m8[5]);
            float m4c = fmaxf(m8[2], m8[6]), m4d = fmaxf(m8[3], m8[7]);
            float mx = fmaxf(fmaxf(m4a, m4b), fmaxf(m4c, m4d));
            // defer-max: full row-max reduce ONLY when threshold exceeded
            if (!__all(mx <= mrun + 11.5f)) {
                mx = fmaxf(mx, __shfl_xor(mx, 16));
                mx = fmaxf(mx, __shfl_xor(mx, 32));
                float mn2 = fmaxf(mrun, mx);
                float sf = exp2f(mrun - mn2);
                mrun = mn2;
                lrun *= sf;
#pragma unroll
                for (int dblk = 0; dblk < 8; ++dblk)
#pragma unroll
                    for (int r = 0; r < 4; ++r)
                        oacc[dblk][r] *= sf;
            }
            float mn = mrun;
            float pr[16];
            float rs = 0.f;
#pragma unroll
            for (int i = 0; i < 16; ++i) {
                pr[i] = exp2f(sv[i] - mn);
                rs += pr[i];
            }
            lrun += rs;    // partial; no cross-lane reduce here
#pragma unroll
            for (int t4 = 0; t4 < 4; ++t4) {
                pk[t4][0] = cvt2bf(pr[t4 * 4 + 0], pr[t4 * 4 + 1]);
                pk[t4][1] = cvt2bf(pr[t4 * 4 + 2], pr[t4 * 4 + 3]);
            }
        }
        // ---- barrier A: all waves done reading K(t); V(t) drained ----
        __syncthreads();
        if (pfv && br == 0) {
            const char* kS = kSrc0 + (size_t)(kt + 1) * 16384;
            gload16(kS,        ldsK);
            gload16(kS + 8192, ldsK + 4096);
            gload16(kS + 1024, ldsK + 8192);
            gload16(kS + 9216, ldsK + 12288);
        }
        // ---- PV (reads V buffer only); P fragment is lane-local ----
#pragma unroll
        for (int h = 0; h < 2; ++h) {
            union { unsigned int uv[4]; bf16x8 v; } pu;
            pu.uv[0] = pk[h][0];
            pu.uv[1] = pk[h][1];
            pu.uv[2] = pk[2 + h][0];
            pu.uv[3] = pk[2 + h][1];
            bf16x8 pb = pu.v;
            __builtin_amdgcn_s_setprio(1);
#pragma unroll
            for (int dblk = 0; dblk < 8; ++dblk) {
                int rv = dblk * 16 + q;
                bf16x8 vf = *(const bf16x8*)(Vb + rv * 128 + ((h * 64 + g4 * 16) ^ ((rv & 7) << 4)));
                oacc[dblk] = __builtin_amdgcn_mfma_f32_16x16x32_bf16(vf, pb, oacc[dblk], 0, 0, 0);
            }
            __builtin_amdgcn_s_setprio(0);
        }
        // ---- barrier B: drains K(t+1); all waves done reading V(t) ----
        __syncthreads();
        if (pfv && br == 1) {
            const char* vS = vSrc0 + (size_t)(kt + 1) * 128;
#pragma unroll
            for (int c = 0; c < 4; ++c)
                gload16(vS + (size_t)c * 147456, ldsV + c * 4096);
        }
    }

    // deferred sum reduce (once): row total = sum of 4 lane partials
    lrun += __shfl_xor(lrun, 16);
    lrun += __shfl_xor(lrun, 32);

    int row = qg * 16 + q;
    if (nch == 1) {
        // exchange branch-1 normalized O through LDS, then br0 does diff+LN
        float inv = 1.f / lrun;
        float* Osh = (float*)smem;
        if (br == 1) {
            int base = qg * 2048 + l;
#pragma unroll
            for (int dblk = 0; dblk < 8; ++dblk)
#pragma unroll
                for (int r = 0; r < 4; ++r)
                    Osh[base + (dblk * 4 + r) * 64] = oacc[dblk][r] * inv;
        }
        __syncthreads();
        if (br == 0) {
            float pa = lq1[l] * lk1[l];
            float pb2 = lq2[l] * lk2[l];
#pragma unroll
            for (int off = 32; off >= 1; off >>= 1) {
                pa += __shfl_xor(pa, off);
                pb2 += __shfl_xor(pb2, off);
            }
            float lam = __expf(pa) - __expf(pb2) + LAMBDA_INIT_F;

            int base = qg * 2048 + l;
            float att[8][4];
            float sm = 0.f;
#pragma unroll
            for (int dblk = 0; dblk < 8; ++dblk)
#pragma unroll
                for (int r = 0; r < 4; ++r) {
                    float a = oacc[dblk][r] * inv - lam * Osh[base + (dblk * 4 + r) * 64];
                    att[dblk][r] = a;
                    sm += a;
                }
            sm += __shfl_xor(sm, 16);
            sm += __shfl_xor(sm, 32);
            float mean = sm * (1.f / 128.f);
            float sv2 = 0.f;
#pragma unroll
            for (int dblk = 0; dblk < 8; ++dblk)
#pragma unroll
                for (int r = 0; r < 4; ++r) {
                    float d = att[dblk][r] - mean;
                    sv2 += d * d;
                }
            sv2 += __shfl_xor(sv2, 16);
            sv2 += __shfl_xor(sv2, 32);
            float rstd = rsqrtf(sv2 * (1.f / 128.f) + 1e-5f);

            float* orow = out + ((size_t)b * T_ + q_g) * 128;
#pragma unroll
            for (int dblk = 0; dblk < 8; ++dblk) {
                int d0 = dblk * 16 + g4 * 4;
                float4 o;
                o.x = (att[dblk][0] - mean) * rstd * g_out[d0 + 0] + b_out[d0 + 0];
                o.y = (att[dblk][1] - mean) * rstd * g_out[d0 + 1] + b_out[d0 + 1];
                o.z = (att[dblk][2] - mean) * rstd * g_out[d0 + 2] + b_out[d0 + 2];
                o.w = (att[dblk][3] - mean) * rstd * g_out[d0 + 3] + b_out[d0 + 3];
                *(float4*)(orow + d0) = o;
            }
        }
    } else {
        // write partials for THIS branch (O bf16, m/l f32; m in base-2 domain)
        int g2 = (j - 6) / 6;
        int off = 6 * g2 * (g2 + 3) / 2 + (j - 6 - 6 * g2) * (g2 + 2);
        int slot = b * 120 + off + ci;
        char* ob = (char*)opart + (size_t)slot * 32768 + br * 16384;
#pragma unroll
        for (int dblk = 0; dblk < 8; ++dblk) {
            uint2 o;
            o.x = pack2bf(oacc[dblk][0], oacc[dblk][1]);
            o.y = pack2bf(oacc[dblk][2], oacc[dblk][3]);
            *(uint2*)(ob + row * 256 + (dblk * 16 + g4 * 4) * 2) = o;
        }
        if (g4 == 0) {
            float2 mlv;
            mlv.x = mrun;
            mlv.y = lrun;
            *(float2*)(mlpart + ((size_t)slot * 128 + br * 64 + row) * 2) = mlv;
        }
    }
}

// ---------------------------------------------------------------------------
// Kernel 5: merge 2-6 KV-split partials per (b, j>=6) + lambda-diff + LN.
// Partials' m is in base-2 domain -> exp2f weights.
// ---------------------------------------------------------------------------
__global__ __launch_bounds__(512) void k_merge(
    const unsigned short* __restrict__ opart,
    const float* __restrict__ mlpart,
    const float* __restrict__ lq1, const float* __restrict__ lq2,
    const float* __restrict__ lk1, const float* __restrict__ lk2,
    const float* __restrict__ g_out, const float* __restrict__ b_out,
    float* __restrict__ out)
{
    int bid = blockIdx.x;
    int b = bid & 7;
    int j = 6 + (bid >> 3);
    int nch = (j + 6) / 6;   // 2..6
    int g2 = (j - 6) / 6;
    int slotb = b * 120 + 6 * g2 * (g2 + 3) / 2 + (j - 6 - 6 * g2) * (g2 + 2);
    int tid = threadIdx.x;
    int row = tid >> 3;
    int d0 = (tid & 7) * 16;
    int l = tid & 63;

    float pa = lq1[l] * lk1[l];
    float pb = lq2[l] * lk2[l];
#pragma unroll
    for (int off = 32; off >= 1; off >>= 1) {
        pa += __shfl_xor(pa, off);
        pb += __shfl_xor(pb, off);
    }
    float lam = __expf(pa) - __expf(pb) + LAMBDA_INIT_F;

    float res[2][16];
#pragma unroll
    for (int br = 0; br < 2; ++br) {
        float mv0 = -1e30f, mv1 = -1e30f, mv2 = -1e30f,
              mv3 = -1e30f, mv4 = -1e30f, mv5 = -1e30f;
        float lv0 = 0.f, lv1 = 0.f, lv2 = 0.f, lv3 = 0.f, lv4 = 0.f, lv5 = 0.f;
        {
            const float* p0 = mlpart + ((size_t)slotb * 128 + br * 64 + row) * 2;
            mv0 = p0[0]; lv0 = p0[1];
            const float* p1 = mlpart + ((size_t)(slotb + 1) * 128 + br * 64 + row) * 2;
            mv1 = p1[0]; lv1 = p1[1];
            if (nch > 2) { const float* p = mlpart + ((size_t)(slotb + 2) * 128 + br * 64 + row) * 2; mv2 = p[0]; lv2 = p[1]; }
            if (nch > 3) { const float* p = mlpart + ((size_t)(slotb + 3) * 128 + br * 64 + row) * 2; mv3 = p[0]; lv3 = p[1]; }
            if (nch > 4) { const float* p = mlpart + ((size_t)(slotb + 4) * 128 + br * 64 + row) * 2; mv4 = p[0]; lv4 = p[1]; }
            if (nch > 5) { const float* p = mlpart + ((size_t)(slotb + 5) * 128 + br * 64 + row) * 2; mv5 = p[0]; lv5 = p[1]; }
        }
        float mstar = fmaxf(fmaxf(fmaxf(mv0, mv1), fmaxf(mv2, mv3)), fmaxf(mv4, mv5));
        float w0 = exp2f(mv0 - mstar);
        float w1 = exp2f(mv1 - mstar);
        float w2 = (nch > 2) ? exp2f(mv2 - mstar) : 0.f;
        float w3 = (nch > 3) ? exp2f(mv3 - mstar) : 0.f;
        float w4 = (nch > 4) ? exp2f(mv4 - mstar) : 0.f;
        float w5 = (nch > 5) ? exp2f(mv5 - mstar) : 0.f;
        float lsum = w0 * lv0 + w1 * lv1 + w2 * lv2 + w3 * lv3 + w4 * lv4 + w5 * lv5;

        float acc[16] = {};
#pragma unroll
        for (int c = 0; c < 6; ++c) {
            if (c >= nch) break;
            float wc = (c == 0) ? w0 : (c == 1) ? w1 : (c == 2) ? w2
                     : (c == 3) ? w3 : (c == 4) ? w4 : w5;
            const char* ob = (const char*)opart + (size_t)(slotb + c) * 32768
                           + br * 16384 + row * 256 + d0 * 2;
            uint4 v0 = *(const uint4*)(ob);
            uint4 v1 = *(const uint4*)(ob + 16);
            const unsigned int vv[8] = {v0.x, v0.y, v0.z, v0.w, v1.x, v1.y, v1.z, v1.w};
#pragma unroll
            for (int i = 0; i < 8; ++i) {
                acc[i * 2]     += wc * bf2f((unsigned short)(vv[i] & 0xFFFF));
                acc[i * 2 + 1] += wc * bf2f((unsigned short)(vv[i] >> 16));
            }
        }
        float inv = 1.f / lsum;
#pragma unroll
        for (int i = 0; i < 16; ++i) res[br][i] = acc[i] * inv;
    }

    float att[16];
    float sm = 0.f;
#pragma unroll
    for (int i = 0; i < 16; ++i) {
        att[i] = res[0][i] - lam * res[1][i];
        sm += att[i];
    }
    sm += __shfl_xor(sm, 1);
    sm += __shfl_xor(sm, 2);
    sm += __shfl_xor(sm, 4);
    float mean = sm * (1.f / 128.f);
    float sv2 = 0.f;
#pragma unroll
    for (int i = 0; i < 16; ++i) {
        float d = att[i] - mean;
        sv2 += d * d;
    }
    sv2 += __shfl_xor(sv2, 1);
    sv2 += __shfl_xor(sv2, 2);
    sv2 += __shfl_xor(sv2, 4);
    float rstd = rsqrtf(sv2 * (1.f / 128.f) + 1e-5f);

    float* orow = out + ((size_t)b * T_ + j * 64 + row) * 128 + d0;
#pragma unroll
    for (int k = 0; k < 4; ++k) {
        float4 o;
        o.x = (att[k * 4 + 0] - mean) * rstd * g_out[d0 + k * 4 + 0] + b_out[d0 + k * 4 + 0];
        o.y = (att[k * 4 + 1] - mean) * rstd * g_out[d0 + k * 4 + 1] + b_out[d0 + k * 4 + 1];
        o.z = (att[k * 4 + 2] - mean) * rstd * g_out[d0 + k * 4 + 2] + b_out[d0 + k * 4 + 2];
        o.w = (att[k * 4 + 3] - mean) * rstd * g_out[d0 + k * 4 + 3] + b_out[d0 + k * 4 + 3];
        *(float4*)(orow + k * 4) = o;
    }
}

extern "C" void kernel_launch(void* const* d_in, const int* in_sizes, int n_in,
                              void* d_out, int out_size, void* d_ws, size_t ws_size,
                              hipStream_t stream) {
    (void)in_sizes; (void)n_in; (void)out_size; (void)ws_size;
    const float* x = (const float*)d_in[0];
    char* ws = (char*)d_ws;
    unsigned short* wt  = (unsigned short*)ws;                      // 2,359,296 B
    unsigned short* xbf = (unsigned short*)(ws + 2359296);          // 37,748,736 B
    unsigned short* qo  = (unsigned short*)(ws + 40108032);         // 4,718,592 B
    unsigned short* ko  = (unsigned short*)(ws + 44826624);         // 4,718,592 B
    unsigned short* vto = (unsigned short*)(ws + 49545216);         // 4,718,592 B
    // partials alias the dead xbf region (xbf unused after k_proj2):
    unsigned short* opart = (unsigned short*)(ws + 2359296);        // 960*32768 = 31,457,280 B
    float*          mlpart = (float*)(ws + 2359296 + 31457280);     // 960*1024  =    983,040 B

    hipLaunchKernelGGL(k_wtrans, dim3(288), dim3(256), 0, stream,
        (const float*)d_in[4], (const float*)d_in[5], (const float*)d_in[6],
        (const float*)d_in[1], (const float*)d_in[2], (const float*)d_in[3],
        (const float*)d_in[7], (const float*)d_in[8], (const float*)d_in[9], wt);

    hipLaunchKernelGGL(k_ln, dim3(4608), dim3(256), 0, stream,
        x,
        (const float*)d_in[10], (const float*)d_in[11],
        (const float*)d_in[12], (const float*)d_in[13],
        (const float*)d_in[14], (const float*)d_in[15],
        xbf);

    hipLaunchKernelGGL(k_proj2, dim3(288), dim3(512), 0, stream,
        xbf, wt, qo, ko, vto);

    hipLaunchKernelGGL(k_attn, dim3(1008), dim3(512), 0, stream,
        qo, ko, vto,
        (const float*)d_in[18], (const float*)d_in[19],
        (const float*)d_in[20], (const float*)d_in[21],
        (const float*)d_in[16], (const float*)d_in[17],
        opart, mlpart,
        (float*)d_out);

    hipLaunchKernelGGL(k_merge, dim3(240), dim3(512), 0, stream,
        opart, mlpart,
        (const float*)d_in[18], (const float*)d_in[19],
        (const float*)d_in[20], (const float*)d_in[21],
        (const float*)d_in[16], (const float*)d_in[17],
        (float*)d_out);
}

// Round 17
// 113.086 us; speedup vs baseline: 1.0165x; 1.0165x over previous
//
#include <hip/hip_runtime.h>
#include <hip/hip_bf16.h>
#include <stdint.h>

#define B_ 8
#define T_ 2304
#define DIN 1024
#define LAMBDA_INIT_F 0.6192834728526788f
#define QSCALE 0.1803368801111137f   // 0.125 * log2(e); softmax runs in base-2

typedef __bf16 bf16x8 __attribute__((ext_vector_type(8)));
typedef float f32x4 __attribute__((ext_vector_type(4)));

__device__ __forceinline__ unsigned short f2bf(float f) {
    union { float f; unsigned int u; } v; v.f = f;
    unsigned int u = v.u;
    unsigned int r = (u + 0x7FFFu + ((u >> 16) & 1u)) >> 16;
    return (unsigned short)r;
}

__device__ __forceinline__ unsigned int pack2bf(float lo, float hi) {
    return ((unsigned int)f2bf(hi) << 16) | (unsigned int)f2bf(lo);
}

// native bf16 pair conversion (compiler emits v_cvt, fuses pairs)
__device__ __forceinline__ unsigned int cvt2bf(float lo, float hi) {
    union { __bf16 h[2]; unsigned int u; } v;
    v.h[0] = (__bf16)lo; v.h[1] = (__bf16)hi;
    return v.u;
}

__device__ __forceinline__ float bf2f(unsigned short u) {
    union { unsigned int u; float f; } v; v.u = ((unsigned int)u) << 16;
    return v.f;
}

// async 16B global->LDS (lane i writes lds_base + i*16; lds base wave-uniform)
__device__ __forceinline__ void gload16(const void* g, void* l) {
    __builtin_amdgcn_global_load_lds(
        (const __attribute__((address_space(1))) unsigned int*)g,
        (__attribute__((address_space(3))) unsigned int*)l,
        16, 0, 0);
}

// ---------------------------------------------------------------------------
// Kernel 1: transpose 9 weight mats (1024x128 f32) -> WT[seg][384][1024] bf16
// ---------------------------------------------------------------------------
__global__ __launch_bounds__(256) void k_wtrans(
    const float* w0, const float* w1, const float* w2,
    const float* w3, const float* w4, const float* w5,
    const float* w6, const float* w7, const float* w8,
    unsigned short* __restrict__ wt)
{
    __shared__ float tile[64][65];
    int bx = blockIdx.x;
    int mat = bx >> 5;
    int tl = bx & 31;
    int tx = tl & 15;
    int ty = tl >> 4;
    const float* srcs[9] = {w0, w1, w2, w3, w4, w5, w6, w7, w8};
    const float* src = srcs[mat];
    int k0 = tx * 64, c0 = ty * 64;
    int t = threadIdx.x;
    int r = t >> 2, cg = (t & 3) << 4;
    const float* p = src + (size_t)(k0 + r) * 128 + c0 + cg;
#pragma unroll
    for (int i = 0; i < 4; ++i) {
        float4 v = *(const float4*)(p + i * 4);
        tile[r][cg + i * 4 + 0] = v.x;
        tile[r][cg + i * 4 + 1] = v.y;
        tile[r][cg + i * 4 + 2] = v.z;
        tile[r][cg + i * 4 + 3] = v.w;
    }
    __syncthreads();
    int seg = mat / 3, m = mat % 3;
    int crow = seg * 384 + m * 128 + c0 + r;
    unsigned short* dst = wt + (size_t)crow * 1024 + k0 + cg;
    __align__(16) unsigned short ob[16];
#pragma unroll
    for (int i = 0; i < 16; ++i) ob[i] = f2bf(tile[cg + i][r]);
    *(uint4*)(dst) = *(const uint4*)(ob);
    *(uint4*)(dst + 8) = *(const uint4*)(ob + 8);
}

// ---------------------------------------------------------------------------
// Kernel 2: streaming LayerNorm: x f32 -> xbf bf16 [18432][1024].
// ---------------------------------------------------------------------------
__global__ __launch_bounds__(256) void k_ln(
    const float* __restrict__ x,
    const float* __restrict__ g_in, const float* __restrict__ b_in,
    const float* __restrict__ g_ss, const float* __restrict__ b_ss,
    const float* __restrict__ g_se, const float* __restrict__ b_se,
    unsigned short* __restrict__ xbf)
{
    int row = (blockIdx.x << 2) + (threadIdx.x >> 6);
    int l = threadIdx.x & 63;
    int t = row % T_;
    const float* gv; const float* bv;
    if (t < 128)       { gv = g_ss; bv = b_ss; }
    else if (t < 2176) { gv = g_in; bv = b_in; }
    else               { gv = g_se; bv = b_se; }
    const float* xp = x + (size_t)row * DIN + l * 4;
    float4 v0 = *(const float4*)(xp);
    float4 v1 = *(const float4*)(xp + 256);
    float4 v2 = *(const float4*)(xp + 512);
    float4 v3 = *(const float4*)(xp + 768);
    float s  = v0.x + v0.y + v0.z + v0.w + v1.x + v1.y + v1.z + v1.w
             + v2.x + v2.y + v2.z + v2.w + v3.x + v3.y + v3.z + v3.w;
    float s2 = v0.x*v0.x + v0.y*v0.y + v0.z*v0.z + v0.w*v0.w
             + v1.x*v1.x + v1.y*v1.y + v1.z*v1.z + v1.w*v1.w
             + v2.x*v2.x + v2.y*v2.y + v2.z*v2.z + v2.w*v2.w
             + v3.x*v3.x + v3.y*v3.y + v3.z*v3.z + v3.w*v3.w;
#pragma unroll
    for (int off = 1; off <= 32; off <<= 1) {
        s  += __shfl_xor(s,  off);
        s2 += __shfl_xor(s2, off);
    }
    float mean = s * (1.f / 1024.f);
    float rstd = rsqrtf(s2 * (1.f / 1024.f) - mean * mean + 1e-5f);
    unsigned short* op = xbf + (size_t)row * DIN + l * 4;
    const float* gp = gv + l * 4;
    const float* bp = bv + l * 4;
#pragma unroll
    for (int k = 0; k < 4; ++k) {
        float4 vv = (k == 0) ? v0 : (k == 1) ? v1 : (k == 2) ? v2 : v3;
        float4 gk = *(const float4*)(gp + k * 256);
        float4 bk = *(const float4*)(bp + k * 256);
        uint2 o;
        o.x = pack2bf((vv.x - mean) * rstd * gk.x + bk.x,
                      (vv.y - mean) * rstd * gk.y + bk.y);
        o.y = pack2bf((vv.z - mean) * rstd * gk.z + bk.z,
                      (vv.w - mean) * rstd * gk.w + bk.w);
        *(uint2*)(op + k * 256) = o;
    }
}

// ---------------------------------------------------------------------------
// Kernel 3: pure bf16 GEMM: C[18432][384] = xbf @ wt[seg]^T.
// q outputs pre-scaled by 0.125*log2e (softmax in base-2 downstream).
// ---------------------------------------------------------------------------
__global__ __launch_bounds__(512, 4) void k_proj2(
    const unsigned short* __restrict__ xbf,
    const unsigned short* __restrict__ wt,
    unsigned short* __restrict__ qo,
    unsigned short* __restrict__ ko,
    unsigned short* __restrict__ vto)
{
    __shared__ __align__(16) char smem[81920];

    int bid = blockIdx.x;
    int mt = bid >> 1, ch = bid & 1;
    int bb = mt / 18, tt = mt % 18;
    int seg = (tt == 0) ? 0 : ((tt < 17) ? 1 : 2);
    size_t arow0 = (size_t)mt * 128;
    int ncol0 = ch * 192;
    int wrow0 = seg * 384 + ncol0;

    int tid = threadIdx.x;
    int w = tid >> 6, l = tid & 63;
    int wr = w >> 2, wc = w & 3;
    int g4 = l >> 4, cr = l & 15;

    int rA0 = tid >> 3, cS = (tid & 7) << 4;
    const char* srcA0 = (const char*)xbf + (arow0 + rA0) * 2048 + cS;
    const char* srcA1 = srcA0 + (size_t)64 * 2048;
    int dA0 = rA0 * 128 + (cS ^ ((rA0 & 7) << 4));
    int dA1 = dA0 + 64 * 128;
    const char* srcW0 = (const char*)wt + (size_t)(wrow0 + rA0) * 2048 + cS;
    const char* srcW1 = srcW0 + (size_t)64 * 2048;
    const char* srcW2 = srcW0 + (size_t)128 * 2048;
    int dW0 = dA0, dW1 = dA0 + 64 * 128, dW2 = dA0 + 128 * 128;

    {
        uint4 a0 = *(const uint4*)srcA0;
        uint4 a1 = *(const uint4*)srcA1;
        uint4 w0 = *(const uint4*)srcW0;
        uint4 w1 = *(const uint4*)srcW1;
        uint4 w2 = *(const uint4*)srcW2;
        *(uint4*)(smem + dA0) = a0;
        *(uint4*)(smem + dA1) = a1;
        *(uint4*)(smem + 32768 + dW0) = w0;
        *(uint4*)(smem + 32768 + dW1) = w1;
        *(uint4*)(smem + 32768 + dW2) = w2;
    }
    __syncthreads();

    f32x4 acc[4][3] = {};
    for (int ks = 0; ks < 16; ++ks) {
        bool pf = (ks < 15);
        uint4 pa0, pa1, pw0, pw1, pw2;
        if (pf) {
            size_t o = (size_t)(ks + 1) * 128;
            pa0 = *(const uint4*)(srcA0 + o);
            pa1 = *(const uint4*)(srcA1 + o);
            pw0 = *(const uint4*)(srcW0 + o);
            pw1 = *(const uint4*)(srcW1 + o);
            pw2 = *(const uint4*)(srcW2 + o);
        }
        const char* Ab = smem + (ks & 1) * 16384;
        const char* Wb = smem + 32768 + (ks & 1) * 24576;
        __builtin_amdgcn_s_setprio(1);
#pragma unroll
        for (int kk = 0; kk < 2; ++kk) {
            int kb = kk * 64 + g4 * 16;
            bf16x8 af[4];
#pragma unroll
            for (int r4 = 0; r4 < 4; ++r4) {
                int rr = wr * 64 + r4 * 16 + cr;
                af[r4] = *(const bf16x8*)(Ab + rr * 128 + (kb ^ ((rr & 7) << 4)));
            }
            bf16x8 bfr[3];
#pragma unroll
            for (int nt = 0; nt < 3; ++nt) {
                int c = wc * 48 + nt * 16 + cr;
                bfr[nt] = *(const bf16x8*)(Wb + c * 128 + (kb ^ ((c & 7) << 4)));
            }
#pragma unroll
            for (int r4 = 0; r4 < 4; ++r4)
#pragma unroll
                for (int nt = 0; nt < 3; ++nt)
                    acc[r4][nt] = __builtin_amdgcn_mfma_f32_16x16x32_bf16(af[r4], bfr[nt], acc[r4][nt], 0, 0, 0);
        }
        __builtin_amdgcn_s_setprio(0);
        __syncthreads();
        if (pf) {
            char* An = smem + ((ks + 1) & 1) * 16384;
            char* Wn = smem + 32768 + ((ks + 1) & 1) * 24576;
            *(uint4*)(An + dA0) = pa0;
            *(uint4*)(An + dA1) = pa1;
            *(uint4*)(Wn + dW0) = pw0;
            *(uint4*)(Wn + dW1) = pw1;
            *(uint4*)(Wn + dW2) = pw2;
        }
        __syncthreads();
    }

#pragma unroll
    for (int r4 = 0; r4 < 4; ++r4) {
        size_t grow = arow0 + wr * 64 + r4 * 16 + g4 * 4;
#pragma unroll
        for (int nt = 0; nt < 3; ++nt) {
            int c = ncol0 + wc * 48 + nt * 16 + cr;
            f32x4 a = acc[r4][nt];
            if (c < 128) {
#pragma unroll
                for (int g = 0; g < 4; ++g)
                    qo[(grow + g) * 128 + c] = f2bf(a[g] * QSCALE);
            } else if (c < 256) {
#pragma unroll
                for (int g = 0; g < 4; ++g)
                    ko[(grow + g) * 128 + (c - 128)] = f2bf(a[g]);
            } else {
                int cv = c - 256;
                int trow = tt * 128 + wr * 64 + r4 * 16 + g4 * 4;
                uint2 o;
                o.x = pack2bf(a[0], a[1]);
                o.y = pack2bf(a[2], a[3]);
                *(uint2*)(vto + ((size_t)bb * 128 + cv) * T_ + trow) = o;
            }
        }
    }
}

// ---------------------------------------------------------------------------
// Kernel 4: causal diff flash-attention, shuffle-free PV + deferred softmax
// reductions. __launch_bounds__(256, 3): cap 170 regs >= ~148 true demand
// (84 arch VGPR + 64 acc, unified file) -> no spill. 3 blocks/CU.
// CHAMPION CONFIG (R12/R15: 47 us, total 113.1 us).
// ---------------------------------------------------------------------------
__global__ __launch_bounds__(256, 3) void k_attn(
    const unsigned short* __restrict__ qp_,
    const unsigned short* __restrict__ kp_,
    const unsigned short* __restrict__ vp_,
    const float* __restrict__ lq1, const float* __restrict__ lq2,
    const float* __restrict__ lk1, const float* __restrict__ lk2,
    const float* __restrict__ g_out, const float* __restrict__ b_out,
    unsigned short* __restrict__ opart,
    float* __restrict__ mlpart,
    float* __restrict__ out)
{
    __shared__ __align__(16) char smem[32768];   // K 16KB | V 16KB

    int bid = blockIdx.x;
    int b = bid & 7;
    int u = 125 - (bid >> 3);    // big chunks launch first
    int j, ci;
    if (u < 6) { j = u; ci = 0; }
    else {
        int v = u - 6;
        int g, base;
        if (v < 12)      { g = 0; base = 0;  }
        else if (v < 30) { g = 1; base = 12; }
        else if (v < 54) { g = 2; base = 30; }
        else if (v < 84) { g = 3; base = 54; }
        else             { g = 4; base = 84; }
        int w2 = v - base;
        int per = g + 2;
        int qd = w2 / per;
        j = 6 * (g + 1) + qd;
        ci = w2 - qd * per;
    }
    int nch = (j + 6) / 6;
    int c0 = ci * 6;
    int ntile = min(6, j + 1 - c0);
    int t0 = j * 64;

    int tid = threadIdx.x;
    int qg = tid >> 6;           // wave id
    int l = tid & 63;
    int g4 = l >> 4, q = l & 15;
    int q_g = t0 + qg * 16 + q;

    // ---- gload_lds staging map (K rows permuted for shuffle-free PV) ----
    int ldsRowK = qg * 4 + (l >> 4);
    const char* kSrc0 = (const char*)kp_
                      + ((size_t)b * T_ + qg * 8 + (l >> 4)) * 256
                      + (((l & 15) << 4) ^ ((ldsRowK & 7) << 4));
    int rbV = qg * 8 + (l >> 3);
    const char* vSrc0 = (const char*)vp_ + ((size_t)b * 128 + rbV) * (T_ * 2)
                      + (((l & 7) << 4) ^ ((rbV & 7) << 4));
    char* ldsK = smem + qg * 1024;
    char* ldsV = smem + 16384 + qg * 1024;

    // Q B-fragments (held all kernel)
    bf16x8 qf[2][2];
#pragma unroll
    for (int br = 0; br < 2; ++br)
#pragma unroll
        for (int h = 0; h < 2; ++h)
            qf[br][h] = *(const bf16x8*)(qp_ + ((size_t)b * T_ + q_g) * 128 + br * 64 + h * 32 + g4 * 8);

    // prologue: stage tile c0
    {
        const char* kS = kSrc0 + (size_t)c0 * 16384;
        const char* vS = vSrc0 + (size_t)c0 * 128;
        gload16(kS,        ldsK);
        gload16(kS + 8192, ldsK + 4096);
        gload16(kS + 1024, ldsK + 8192);
        gload16(kS + 9216, ldsK + 12288);
#pragma unroll
        for (int c = 0; c < 4; ++c)
            gload16(vS + (size_t)c * 147456, ldsV + c * 4096);
    }
    __syncthreads();

    float mrun[2] = {-1e30f, -1e30f};
    float lrun[2] = {0.f, 0.f};     // per-lane PARTIAL sums (reduced at end)
    f32x4 oacc[2][8] = {};
    const char* Kb = smem;
    const char* Vb = smem + 16384;

    for (int t = 0; t < ntile; ++t) {
        int kt = c0 + t;
        bool diag = (kt == j);
        bool pfv = (t + 1 < ntile);
        unsigned int pk[2][4][2];
        // ---- QK + softmax (reads K buffer only) ----
#pragma unroll
        for (int br = 0; br < 2; ++br) {
            f32x4 s[4] = {};
            __builtin_amdgcn_s_setprio(1);
#pragma unroll
            for (int h = 0; h < 2; ++h) {
#pragma unroll
                for (int t4 = 0; t4 < 4; ++t4) {
                    int rk = t4 * 16 + q;
                    bf16x8 kf = *(const bf16x8*)(Kb + rk * 256 + ((br * 128 + h * 64 + g4 * 16) ^ ((rk & 7) << 4)));
                    s[t4] = __builtin_amdgcn_mfma_f32_16x16x32_bf16(kf, qf[br][h], s[t4], 0, 0, 0);
                }
            }
            __builtin_amdgcn_s_setprio(0);
            float sv[16];
#pragma unroll
            for (int t4 = 0; t4 < 4; ++t4)
#pragma unroll
                for (int r = 0; r < 4; ++r) {
                    float v = s[t4][r];
                    if (diag) {
                        int kv_g = kt * 64 + (t4 & 1) * 32 + g4 * 8 + (t4 >> 1) * 4 + r;
                        if (kv_g > q_g) v = -1e30f;
                    }
                    sv[t4 * 4 + r] = v;
                }
            // tree max over this lane's 16 values (partial row max)
            float m8[8];
#pragma unroll
            for (int i = 0; i < 8; ++i) m8[i] = fmaxf(sv[i], sv[i + 8]);
            float m4a = fmaxf(m8[0], m8[4]), m4b = fmaxf(m8[1], m8[5]);
            float m4c = fmaxf(m8[2], m8[6]), m4d = fmaxf(m8[3], m8[7]);
            float mx = fmaxf(fmaxf(m4a, m4b), fmaxf(m4c, m4d));
            // defer-max: full row-max reduce ONLY when threshold exceeded
            if (!__all(mx <= mrun[br] + 11.5f)) {
                mx = fmaxf(mx, __shfl_xor(mx, 16));
                mx = fmaxf(mx, __shfl_xor(mx, 32));
                float mn2 = fmaxf(mrun[br], mx);
                float sf = exp2f(mrun[br] - mn2);
                mrun[br] = mn2;
                lrun[br] *= sf;
#pragma unroll
                for (int dblk = 0; dblk < 8; ++dblk)
#pragma unroll
                    for (int r = 0; r < 4; ++r)
                        oacc[br][dblk][r] *= sf;
            }
            float mn = mrun[br];
            float pr[16];
            float rs = 0.f;
#pragma unroll
            for (int i = 0; i < 16; ++i) {
                pr[i] = exp2f(sv[i] - mn);
                rs += pr[i];
            }
            lrun[br] += rs;    // partial; no cross-lane reduce here
#pragma unroll
            for (int t4 = 0; t4 < 4; ++t4) {
                pk[br][t4][0] = cvt2bf(pr[t4 * 4 + 0], pr[t4 * 4 + 1]);
                pk[br][t4][1] = cvt2bf(pr[t4 * 4 + 2], pr[t4 * 4 + 3]);
            }
        }
        // ---- barrier A: all waves done reading K(t) ----
        __syncthreads();
        if (pfv) {
            const char* kS = kSrc0 + (size_t)(kt + 1) * 16384;
            gload16(kS,        ldsK);
            gload16(kS + 8192, ldsK + 4096);
            gload16(kS + 1024, ldsK + 8192);
            gload16(kS + 9216, ldsK + 12288);
        }
        // ---- PV (reads V buffer only); P fragment is lane-local ----
#pragma unroll
        for (int h = 0; h < 2; ++h) {
            bf16x8 pb[2];
#pragma unroll
            for (int br = 0; br < 2; ++br) {
                union { unsigned int uv[4]; bf16x8 v; } pu;
                pu.uv[0] = pk[br][h][0];
                pu.uv[1] = pk[br][h][1];
                pu.uv[2] = pk[br][2 + h][0];
                pu.uv[3] = pk[br][2 + h][1];
                pb[br] = pu.v;
            }
            __builtin_amdgcn_s_setprio(1);
#pragma unroll
            for (int dblk = 0; dblk < 8; ++dblk) {
                int rv = dblk * 16 + q;
                bf16x8 vf = *(const bf16x8*)(Vb + rv * 128 + ((h * 64 + g4 * 16) ^ ((rv & 7) << 4)));
                oacc[0][dblk] = __builtin_amdgcn_mfma_f32_16x16x32_bf16(vf, pb[0], oacc[0][dblk], 0, 0, 0);
                oacc[1][dblk] = __builtin_amdgcn_mfma_f32_16x16x32_bf16(vf, pb[1], oacc[1][dblk], 0, 0, 0);
            }
            __builtin_amdgcn_s_setprio(0);
        }
        // ---- barrier B: drains K(t+1); all waves done reading V(t) ----
        __syncthreads();
        if (pfv) {
            const char* vS = vSrc0 + (size_t)(kt + 1) * 128;
#pragma unroll
            for (int c = 0; c < 4; ++c)
                gload16(vS + (size_t)c * 147456, ldsV + c * 4096);
        }
    }

    // deferred sum reduce (once): row total = sum of 4 lane partials
#pragma unroll
    for (int br = 0; br < 2; ++br) {
        lrun[br] += __shfl_xor(lrun[br], 16);
        lrun[br] += __shfl_xor(lrun[br], 32);
    }

    int row = qg * 16 + q;
    if (nch == 1) {
        // direct epilogue: lambda + diff + output LN
        float pa = lq1[l] * lk1[l];
        float pb2 = lq2[l] * lk2[l];
#pragma unroll
        for (int off = 32; off >= 1; off >>= 1) {
            pa += __shfl_xor(pa, off);
            pb2 += __shfl_xor(pb2, off);
        }
        float lam = __expf(pa) - __expf(pb2) + LAMBDA_INIT_F;

        float att[8][4];
        float sm = 0.f;
        float inv1 = 1.f / lrun[0], inv2 = 1.f / lrun[1];
#pragma unroll
        for (int dblk = 0; dblk < 8; ++dblk)
#pragma unroll
            for (int r = 0; r < 4; ++r) {
                float a = oacc[0][dblk][r] * inv1 - lam * (oacc[1][dblk][r] * inv2);
                att[dblk][r] = a;
                sm += a;
            }
        sm += __shfl_xor(sm, 16);
        sm += __shfl_xor(sm, 32);
        float mean = sm * (1.f / 128.f);
        float sv2 = 0.f;
#pragma unroll
        for (int dblk = 0; dblk < 8; ++dblk)
#pragma unroll
            for (int r = 0; r < 4; ++r) {
                float d = att[dblk][r] - mean;
                sv2 += d * d;
            }
        sv2 += __shfl_xor(sv2, 16);
        sv2 += __shfl_xor(sv2, 32);
        float rstd = rsqrtf(sv2 * (1.f / 128.f) + 1e-5f);

        float* orow = out + ((size_t)b * T_ + q_g) * 128;
#pragma unroll
        for (int dblk = 0; dblk < 8; ++dblk) {
            int d0 = dblk * 16 + g4 * 4;
            float4 o;
            o.x = (att[dblk][0] - mean) * rstd * g_out[d0 + 0] + b_out[d0 + 0];
            o.y = (att[dblk][1] - mean) * rstd * g_out[d0 + 1] + b_out[d0 + 1];
            o.z = (att[dblk][2] - mean) * rstd * g_out[d0 + 2] + b_out[d0 + 2];
            o.w = (att[dblk][3] - mean) * rstd * g_out[d0 + 3] + b_out[d0 + 3];
            *(float4*)(orow + d0) = o;
        }
    } else {
        // write partials (O bf16, m/l f32; m in base-2 domain)
        int g2 = (j - 6) / 6;
        int off = 6 * g2 * (g2 + 3) / 2 + (j - 6 - 6 * g2) * (g2 + 2);
        int slot = b * 120 + off + ci;
        char* ob = (char*)opart + (size_t)slot * 32768;
#pragma unroll
        for (int br = 0; br < 2; ++br) {
#pragma unroll
            for (int dblk = 0; dblk < 8; ++dblk) {
                uint2 o;
                o.x = pack2bf(oacc[br][dblk][0], oacc[br][dblk][1]);
                o.y = pack2bf(oacc[br][dblk][2], oacc[br][dblk][3]);
                *(uint2*)(ob + br * 16384 + row * 256 + (dblk * 16 + g4 * 4) * 2) = o;
            }
            if (g4 == 0) {
                float2 mlv;
                mlv.x = mrun[br];
                mlv.y = lrun[br];
                *(float2*)(mlpart + ((size_t)slot * 128 + br * 64 + row) * 2) = mlv;
            }
        }
    }
}

// ---------------------------------------------------------------------------
// Kernel 5: merge 2-6 KV-split partials per (b, j>=6) + lambda-diff + LN.
// Partials' m is in base-2 domain -> exp2f weights.
// ---------------------------------------------------------------------------
__global__ __launch_bounds__(512) void k_merge(
    const unsigned short* __restrict__ opart,
    const float* __restrict__ mlpart,
    const float* __restrict__ lq1, const float* __restrict__ lq2,
    const float* __restrict__ lk1, const float* __restrict__ lk2,
    const float* __restrict__ g_out, const float* __restrict__ b_out,
    float* __restrict__ out)
{
    int bid = blockIdx.x;
    int b = bid & 7;
    int j = 6 + (bid >> 3);
    int nch = (j + 6) / 6;   // 2..6
    int g2 = (j - 6) / 6;
    int slotb = b * 120 + 6 * g2 * (g2 + 3) / 2 + (j - 6 - 6 * g2) * (g2 + 2);
    int tid = threadIdx.x;
    int row = tid >> 3;
    int d0 = (tid & 7) * 16;
    int l = tid & 63;

    float pa = lq1[l] * lk1[l];
    float pb = lq2[l] * lk2[l];
#pragma unroll
    for (int off = 32; off >= 1; off >>= 1) {
        pa += __shfl_xor(pa, off);
        pb += __shfl_xor(pb, off);
    }
    float lam = __expf(pa) - __expf(pb) + LAMBDA_INIT_F;

    float res[2][16];
#pragma unroll
    for (int br = 0; br < 2; ++br) {
        float mv0 = -1e30f, mv1 = -1e30f, mv2 = -1e30f,
              mv3 = -1e30f, mv4 = -1e30f, mv5 = -1e30f;
        float lv0 = 0.f, lv1 = 0.f, lv2 = 0.f, lv3 = 0.f, lv4 = 0.f, lv5 = 0.f;
        {
            const float* p0 = mlpart + ((size_t)slotb * 128 + br * 64 + row) * 2;
            mv0 = p0[0]; lv0 = p0[1];
            const float* p1 = mlpart + ((size_t)(slotb + 1) * 128 + br * 64 + row) * 2;
            mv1 = p1[0]; lv1 = p1[1];
            if (nch > 2) { const float* p = mlpart + ((size_t)(slotb + 2) * 128 + br * 64 + row) * 2; mv2 = p[0]; lv2 = p[1]; }
            if (nch > 3) { const float* p = mlpart + ((size_t)(slotb + 3) * 128 + br * 64 + row) * 2; mv3 = p[0]; lv3 = p[1]; }
            if (nch > 4) { const float* p = mlpart + ((size_t)(slotb + 4) * 128 + br * 64 + row) * 2; mv4 = p[0]; lv4 = p[1]; }
            if (nch > 5) { const float* p = mlpart + ((size_t)(slotb + 5) * 128 + br * 64 + row) * 2; mv5 = p[0]; lv5 = p[1]; }
        }
        float mstar = fmaxf(fmaxf(fmaxf(mv0, mv1), fmaxf(mv2, mv3)), fmaxf(mv4, mv5));
        float w0 = exp2f(mv0 - mstar);
        float w1 = exp2f(mv1 - mstar);
        float w2 = (nch > 2) ? exp2f(mv2 - mstar) : 0.f;
        float w3 = (nch > 3) ? exp2f(mv3 - mstar) : 0.f;
        float w4 = (nch > 4) ? exp2f(mv4 - mstar) : 0.f;
        float w5 = (nch > 5) ? exp2f(mv5 - mstar) : 0.f;
        float lsum = w0 * lv0 + w1 * lv1 + w2 * lv2 + w3 * lv3 + w4 * lv4 + w5 * lv5;

        float acc[16] = {};
#pragma unroll
        for (int c = 0; c < 6; ++c) {
            if (c >= nch) break;
            float wc = (c == 0) ? w0 : (c == 1) ? w1 : (c == 2) ? w2
                     : (c == 3) ? w3 : (c == 4) ? w4 : w5;
            const char* ob = (const char*)opart + (size_t)(slotb + c) * 32768
                           + br * 16384 + row * 256 + d0 * 2;
            uint4 v0 = *(const uint4*)(ob);
            uint4 v1 = *(const uint4*)(ob + 16);
            const unsigned int vv[8] = {v0.x, v0.y, v0.z, v0.w, v1.x, v1.y, v1.z, v1.w};
#pragma unroll
            for (int i = 0; i < 8; ++i) {
                acc[i * 2]     += wc * bf2f((unsigned short)(vv[i] & 0xFFFF));
                acc[i * 2 + 1] += wc * bf2f((unsigned short)(vv[i] >> 16));
            }
        }
        float inv = 1.f / lsum;
#pragma unroll
        for (int i = 0; i < 16; ++i) res[br][i] = acc[i] * inv;
    }

    float att[16];
    float sm = 0.f;
#pragma unroll
    for (int i = 0; i < 16; ++i) {
        att[i] = res[0][i] - lam * res[1][i];
        sm += att[i];
    }
    sm += __shfl_xor(sm, 1);
    sm += __shfl_xor(sm, 2);
    sm += __shfl_xor(sm, 4);
    float mean = sm * (1.f / 128.f);
    float sv2 = 0.f;
#pragma unroll
    for (int i = 0; i < 16; ++i) {
        float d = att[i] - mean;
        sv2 += d * d;
    }
    sv2 += __shfl_xor(sv2, 1);
    sv2 += __shfl_xor(sv2, 2);
    sv2 += __shfl_xor(sv2, 4);
    float rstd = rsqrtf(sv2 * (1.f / 128.f) + 1e-5f);

    float* orow = out + ((size_t)b * T_ + j * 64 + row) * 128 + d0;
#pragma unroll
    for (int k = 0; k < 4; ++k) {
        float4 o;
        o.x = (att[k * 4 + 0] - mean) * rstd * g_out[d0 + k * 4 + 0] + b_out[d0 + k * 4 + 0];
        o.y = (att[k * 4 + 1] - mean) * rstd * g_out[d0 + k * 4 + 1] + b_out[d0 + k * 4 + 1];
        o.z = (att[k * 4 + 2] - mean) * rstd * g_out[d0 + k * 4 + 2] + b_out[d0 + k * 4 + 2];
        o.w = (att[k * 4 + 3] - mean) * rstd * g_out[d0 + k * 4 + 3] + b_out[d0 + k * 4 + 3];
        *(float4*)(orow + k * 4) = o;
    }
}

extern "C" void kernel_launch(void* const* d_in, const int* in_sizes, int n_in,
                              void* d_out, int out_size, void* d_ws, size_t ws_size,
                              hipStream_t stream) {
    (void)in_sizes; (void)n_in; (void)out_size; (void)ws_size;
    const float* x = (const float*)d_in[0];
    char* ws = (char*)d_ws;
    unsigned short* wt  = (unsigned short*)ws;                      // 2,359,296 B
    unsigned short* xbf = (unsigned short*)(ws + 2359296);          // 37,748,736 B
    unsigned short* qo  = (unsigned short*)(ws + 40108032);         // 4,718,592 B
    unsigned short* ko  = (unsigned short*)(ws + 44826624);         // 4,718,592 B
    unsigned short* vto = (unsigned short*)(ws + 49545216);         // 4,718,592 B
    // partials alias the dead xbf region (xbf unused after k_proj2):
    unsigned short* opart = (unsigned short*)(ws + 2359296);        // 960*32768 = 31,457,280 B
    float*          mlpart = (float*)(ws + 2359296 + 31457280);     // 960*1024  =    983,040 B

    hipLaunchKernelGGL(k_wtrans, dim3(288), dim3(256), 0, stream,
        (const float*)d_in[4], (const float*)d_in[5], (const float*)d_in[6],
        (const float*)d_in[1], (const float*)d_in[2], (const float*)d_in[3],
        (const float*)d_in[7], (const float*)d_in[8], (const float*)d_in[9], wt);

    hipLaunchKernelGGL(k_ln, dim3(4608), dim3(256), 0, stream,
        x,
        (const float*)d_in[10], (const float*)d_in[11],
        (const float*)d_in[12], (const float*)d_in[13],
        (const float*)d_in[14], (const float*)d_in[15],
        xbf);

    hipLaunchKernelGGL(k_proj2, dim3(288), dim3(512), 0, stream,
        xbf, wt, qo, ko, vto);

    hipLaunchKernelGGL(k_attn, dim3(1008), dim3(256), 0, stream,
        qo, ko, vto,
        (const float*)d_in[18], (const float*)d_in[19],
        (const float*)d_in[20], (const float*)d_in[21],
        (const float*)d_in[16], (const float*)d_in[17],
        opart, mlpart,
        (float*)d_out);

    hipLaunchKernelGGL(k_merge, dim3(240), dim3(512), 0, stream,
        opart, mlpart,
        (const float*)d_in[18], (const float*)d_in[19],
        (const float*)d_in[20], (const float*)d_in[21],
        (const float*)d_in[16], (const float*)d_in[17],
        (float*)d_out);
}